// Round 21
// baseline (161.193 us; speedup 1.0000x reference)
//
#include <hip/hip_runtime.h>

// arHOCA: L=200 positions, Q=21 alphabet, H=128 hidden, B=256 batch.
// x is one-hot => all "x @ W" contractions are gather-sums over idx[b,l].
//
// DCA mask (faithful to reference): mask loop is `for i in range(Q)`, so only
// row-blocks 1..20 / col-blocks 0..19 are active; mask[d,c]=1 iff blk(c)<blk(d).
// => DCA affects only output cols j < 441; for positions >= 21 out_dca = bias.
//
// Structure (R17/R20 base, 131.0 us; this round: CH 48->64, NCH 5->4 only):
//  k_idx: one-hot -> uchar idxT.
//  k_h1:  chunked LDS-broadcast streamer (fp32 tile, bf16 partial sums);
//         2 lp per barrier (4 tile buffers).
//  k_h2:  partial-sum + b1 + lrelu A-stage, 128x128x128 fp32 GEMM + b2 + lrelu,
//         fused Wout epilogue; pure-writes out = NN + bout + bias.
//  k_dca: slim (runs LAST): pos 0 pure write, pos 1..20 += DCA gather.
//
// ws layout: idxT [200][256] uchar (51200 B, region reserved to 204800)
//            | part [199][4][256][128] bf16 (52166656 B).

#define Lc   200
#define Qc   21
#define Hc   128
#define Bc   256
#define LQc  4200
#define LM1c 199
#define CH   64    // lp chunk size
#define NCH  4     // max chunks per l

__device__ __forceinline__ unsigned int bf16rne(float f) {
    unsigned int u = __float_as_uint(f);
    return u + 0x7fffu + ((u >> 16) & 1u);   // take high 16 afterwards
}

// ---------------- K0: idxT[l][b] = argmax_c x[b,l,c] (uchar) ----------------
__global__ __launch_bounds__(256) void k_idx(const float* __restrict__ x,
                                             unsigned char* __restrict__ idxT) {
    const int l = blockIdx.x;       // 0..199
    const int b = threadIdx.x;      // 0..255
    const float* p = x + ((size_t)b * Lc + l) * Qc;
    int id = 0;
#pragma unroll
    for (int c = 0; c < Qc; ++c) id = (p[c] > 0.5f) ? c : id;
    idxT[l * Bc + b] = (unsigned char)id;   // coalesced byte store
}

// ---------------- K1 (slim, runs LAST): DCA gather for positions 0..20 ----------------
// pos 0:  out[b,0,q]  = bias[q] + w0[q] + b0[q] + sum_{lr=1..20} DW[lr*Q+idx, q]
// pos>=1: out[b,p,q] += sum_{lr=p+1..20} DW[lr*Q+idx[b,lr], p*Q+q]
__global__ __launch_bounds__(512) void k_dca(const float* __restrict__ DW,
                                             const float* __restrict__ bias,
                                             const float* __restrict__ w0,
                                             const float* __restrict__ b0,
                                             const unsigned char* __restrict__ idxT,
                                             float* __restrict__ out) {
    const int b = blockIdx.x;              // 0..255
    const int t = threadIdx.x;
    __shared__ int sidx[20];
    if (t < 20) sidx[t] = idxT[(t + 1) * Bc + b];
    __syncthreads();
    if (t >= 441) return;
    const int pos = t / 21, q = t - pos * 21;
    const int j = t;                       // j = pos*21 + q
    float acc = 0.f;
    for (int lr = pos + 1; lr <= 20; ++lr)
        acc += DW[(size_t)(lr * Qc + sidx[lr - 1]) * LQc + j];
    float* op = out + (size_t)b * LQc;
    if (pos == 0) op[j] = acc + bias[j] + w0[q] + b0[q];
    else          op[j] += acc;
}

// ---------------- K2: chunked LDS-broadcast partial sums (2 lp / barrier) ----------------
// part[l][c][b][h] = sum_{lp in chunk c, lp<=l} W1[l, lp*Q+idx[b,lp], h]
// Block = (l, chunk), 1024 threads. Thread = (hq 0..31, bg 0..31 of 8 batches).
// Four tile buffers as two ping-pong PAIRS: per loop body consume tiles k,k+1,
// stage k+2,k+3 into the other pair, ONE barrier.
__global__ __launch_bounds__(1024, 2) void k_h1(const float* __restrict__ W1,
                                                const unsigned char* __restrict__ idxT,
                                                unsigned int* __restrict__ part) {
    const int bid = blockIdx.x;            // 0..795
    const int l = 198 - bid / NCH, c = bid % NCH;
    const int lo = c * CH;
    if (lo > l) return;                    // invalid chunk for this l
    const int hi = (l < lo + CH - 1) ? l : lo + CH - 1;
    const int n = hi - lo + 1;             // 1..64 iterations

    const int t = threadIdx.x;
    const int hq = t & 31;                 // h-quad: h = hq*4 .. hq*4+3
    const int bg = t >> 5;                 // batch group: b = bg*8 .. bg*8+7

    __shared__ __align__(16) float tile[4][Qc * 132];  // 2 ping-pong pairs
    __shared__ __align__(16) unsigned char idxs8[CH * Bc];

    // stage chunk idx bytes (n*256 B = n*16 int4), coalesced
    {
        const int4* isrc = (const int4*)(idxT + lo * Bc);
        int4* idst = (int4*)idxs8;
        if (t < n * 16) idst[t] = isrc[t];
    }

    // stage tiles 0 and 1 (672 float4 each): i -> row i>>5, col (i&31)*4
    const float* Wsrc = W1 + (size_t)l * (LQc * Hc) + (size_t)lo * (Qc * Hc);
    const int soff = (t >> 5) * 132 + (t & 31) * 4;
    if (t < 672) {
        *(float4*)&tile[0][soff] = ((const float4*)Wsrc)[t];
        if (n > 1)
            *(float4*)&tile[1][soff] = ((const float4*)(Wsrc + (size_t)(Qc * Hc)))[t];
    }
    __syncthreads();

    float4 acc[8];
#pragma unroll
    for (int j = 0; j < 8; ++j) acc[j] = (float4){0.f, 0.f, 0.f, 0.f};

#define ACCK(TB, KIDX) { \
        const unsigned int* ibw_ = (const unsigned int*)&idxs8[(KIDX) * Bc + bg * 8]; \
        const unsigned int u0_ = ibw_[0], u1_ = ibw_[1]; \
        const float* tb_ = &(TB)[hq * 4]; \
        { const float4 v = *(const float4*)(tb_ + (int)( u0_        & 0xffu) * 132); \
          acc[0].x += v.x; acc[0].y += v.y; acc[0].z += v.z; acc[0].w += v.w; } \
        { const float4 v = *(const float4*)(tb_ + (int)((u0_ >>  8) & 0xffu) * 132); \
          acc[1].x += v.x; acc[1].y += v.y; acc[1].z += v.z; acc[1].w += v.w; } \
        { const float4 v = *(const float4*)(tb_ + (int)((u0_ >> 16) & 0xffu) * 132); \
          acc[2].x += v.x; acc[2].y += v.y; acc[2].z += v.z; acc[2].w += v.w; } \
        { const float4 v = *(const float4*)(tb_ + (int)((u0_ >> 24) & 0xffu) * 132); \
          acc[3].x += v.x; acc[3].y += v.y; acc[3].z += v.z; acc[3].w += v.w; } \
        { const float4 v = *(const float4*)(tb_ + (int)( u1_        & 0xffu) * 132); \
          acc[4].x += v.x; acc[4].y += v.y; acc[4].z += v.z; acc[4].w += v.w; } \
        { const float4 v = *(const float4*)(tb_ + (int)((u1_ >>  8) & 0xffu) * 132); \
          acc[5].x += v.x; acc[5].y += v.y; acc[5].z += v.z; acc[5].w += v.w; } \
        { const float4 v = *(const float4*)(tb_ + (int)((u1_ >> 16) & 0xffu) * 132); \
          acc[6].x += v.x; acc[6].y += v.y; acc[6].z += v.z; acc[6].w += v.w; } \
        { const float4 v = *(const float4*)(tb_ + (int)((u1_ >> 24) & 0xffu) * 132); \
          acc[7].x += v.x; acc[7].y += v.y; acc[7].z += v.z; acc[7].w += v.w; } }

    int cur = 0;                            // current pair: buffers cur*2, cur*2+1
    for (int k = 0; k < n; k += 2) {
        // issue loads for tiles k+2, k+3 (1 float4/thread each)
        float4 p0, p1;
        const bool st0 = (k + 2 < n) && (t < 672);
        const bool st1 = (k + 3 < n) && (t < 672);
        if (st0) p0 = ((const float4*)(Wsrc + (size_t)(k + 2) * (Qc * Hc)))[t];
        if (st1) p1 = ((const float4*)(Wsrc + (size_t)(k + 3) * (Qc * Hc)))[t];
        // consume tiles k (and k+1) — HBM latency of p0/p1 hides under this
        ACCK(tile[cur * 2], k)
        if (k + 1 < n) ACCK(tile[cur * 2 + 1], k + 1)
        // write k+2/k+3 into the other pair, then ONE barrier
        if (st0) *(float4*)&tile[(cur ^ 1) * 2][soff] = p0;
        if (st1) *(float4*)&tile[(cur ^ 1) * 2 + 1][soff] = p1;
        __syncthreads();
        cur ^= 1;
    }
#undef ACCK

    // store partials as bf16: part[(l*4+c)][b][h]; 8B/lane x 32 lanes bursts
    unsigned int* pb = part + ((size_t)(l * NCH + c) * Bc + bg * 8) * (Hc / 2) + hq * 2;
#pragma unroll
    for (int j = 0; j < 8; ++j) {
        const unsigned int d0 = (bf16rne(acc[j].x) >> 16) | (bf16rne(acc[j].y) & 0xffff0000u);
        const unsigned int d1 = (bf16rne(acc[j].z) >> 16) | (bf16rne(acc[j].w) & 0xffff0000u);
        *(uint2*)(pb + (size_t)j * (Hc / 2)) = make_uint2(d0, d1);
    }
}

// ---------------- K3 (fused): h2 GEMM + Wout contraction -> out (pure write) ----------------
// Block = (l, batch-half), 512 threads (3.1 waves/SIMD). XCD-paired dispatch:
// both halves of l on one XCD. Writes out[b,l+1,q] = NN + bout + bias.
__global__ __launch_bounds__(512, 4) void k_h2(const unsigned int* __restrict__ part,
                                               const float* __restrict__ W2,
                                               const float* __restrict__ b1,
                                               const float* __restrict__ b2,
                                               const float* __restrict__ Wout,
                                               const float* __restrict__ bout,
                                               const float* __restrict__ bias,
                                               float* __restrict__ out) {
    const int d = blockIdx.x;              // 0..399
    const int g = d >> 4, r = d & 7, half = (d >> 3) & 1;
    const int l = g * 8 + r;
    if (l >= LM1c) return;                 // 2 idle blocks
    const int bbase = half * 128;
    const int t = threadIdx.x;
    const int tx = t & 15, ty = t >> 4;    // thread tile: 4(m) x 8(n); ty 0..31
    __shared__ float As[16][132];
    __shared__ float Bs[16][Hc];
    __shared__ float Ts[32][132];
    __shared__ float wl[Hc][24];           // Wout[l] padded; cols 21..23 = 0
    __shared__ float blsh[24];             // bout[l] + bias[(l+1)*21+..]; pad 0
    float acc[4][8];
#pragma unroll
    for (int i = 0; i < 4; ++i)
#pragma unroll
        for (int j = 0; j < 8; ++j) acc[i][j] = 0.f;
    // stage Wout[l] (128x21) + zero pad cols; stage fused output bias
    {
        const float* wsrc = Wout + (size_t)l * Hc * Qc;
        for (int i = t; i < Hc * Qc; i += 512) wl[i / Qc][i % Qc] = wsrc[i];
        if (t < Hc) { wl[t][21] = 0.f; wl[t][22] = 0.f; wl[t][23] = 0.f; }
        if (t < Qc) blsh[t] = bout[l * Qc + t] + bias[(l + 1) * Qc + t];
        else if (t < 24) blsh[t] = 0.f;
    }
    const int skk = t >> 5, sms = (t & 31) * 4;   // B-stage: 1 float4/thread
    const int am = t >> 2, akq = (t & 3) * 4;     // A-stage: m=am, k-quad akq
    const int nch = l / CH + 1;
    const unsigned int* pl = part + ((size_t)(l * NCH) * Bc + bbase + am) * (Hc / 2);
    const float* W2l = W2 + (size_t)l * Hc * Hc;
    for (int ks = 0; ks < 8; ++ks) {
        const int kcu = ks * 8 + (t & 3) * 2;     // uint col (2 bf16 per uint)
        float4 a0 = {0.f, 0.f, 0.f, 0.f};
        for (int cc = 0; cc < nch; ++cc) {
            const uint2 w = *(const uint2*)(pl + (size_t)cc * Bc * (Hc / 2) + kcu);
            a0.x += __uint_as_float(w.x << 16);
            a0.y += __uint_as_float(w.x & 0xffff0000u);
            a0.z += __uint_as_float(w.y << 16);
            a0.w += __uint_as_float(w.y & 0xffff0000u);
        }
        const float4 bb = *(const float4*)(b1 + l * Hc + ks * 16 + akq);
        a0.x += bb.x; a0.y += bb.y; a0.z += bb.z; a0.w += bb.w;
        a0.x = (a0.x >= 0.f) ? a0.x : 0.1f * a0.x;
        a0.y = (a0.y >= 0.f) ? a0.y : 0.1f * a0.y;
        a0.z = (a0.z >= 0.f) ? a0.z : 0.1f * a0.z;
        a0.w = (a0.w >= 0.f) ? a0.w : 0.1f * a0.w;
        const int kb = ks * 16 + skk;
        *(float4*)&Bs[skk][sms] = *(const float4*)(W2l + (size_t)kb * Hc + sms);
        As[akq + 0][am] = a0.x; As[akq + 1][am] = a0.y;
        As[akq + 2][am] = a0.z; As[akq + 3][am] = a0.w;
        __syncthreads();
#pragma unroll
        for (int k = 0; k < 16; ++k) {
            float avr[4], bvr[8];
            *(float4*)&avr[0] = *(const float4*)&As[k][ty * 4];
            *(float4*)&bvr[0] = *(const float4*)&Bs[k][tx * 8];
            *(float4*)&bvr[4] = *(const float4*)&Bs[k][tx * 8 + 4];
#pragma unroll
            for (int i = 0; i < 4; ++i)
#pragma unroll
                for (int j = 0; j < 8; ++j) acc[i][j] += avr[i] * bvr[j];
        }
        __syncthreads();
    }
    float bz[8];
    *(float4*)&bz[0] = *(const float4*)(b2 + l * Hc + tx * 8);
    *(float4*)&bz[4] = *(const float4*)(b2 + l * Hc + tx * 8 + 4);
    float res[4][8];
#pragma unroll
    for (int i = 0; i < 4; ++i)
#pragma unroll
        for (int j = 0; j < 8; ++j) {
            float v = acc[i][j] + bz[j];
            res[i][j] = (v >= 0.f) ? v : 0.1f * v;
        }
    // Epilogue: out[b, l+1, q] = sum_n res_T[n][m] * wl[n][q] + blsh[q].
    const int m = t & 127, qh = t >> 7;    // qh 0..3, wave-uniform
    const int q0 = qh * 6;                 // q 0..5 / 6..11 / 12..17 / 18..23(pad)
    float racc[6];
#pragma unroll
    for (int qi = 0; qi < 6; ++qi) racc[qi] = 0.f;
    for (int c = 0; c < 4; ++c) {
        if ((tx >> 2) == c) {
#pragma unroll
            for (int i = 0; i < 4; ++i)
#pragma unroll
                for (int j = 0; j < 8; ++j) Ts[(tx & 3) * 8 + j][ty * 4 + i] = res[i][j];
        }
        __syncthreads();
#pragma unroll 4
        for (int rr = 0; rr < 32; ++rr) {
            const float v = Ts[rr][m];     // 64 consecutive m per wave: free
            const float* wr = &wl[c * 32 + rr][q0];  // wave-uniform: broadcast
#pragma unroll
            for (int qi = 0; qi < 6; ++qi) racc[qi] += v * wr[qi];
        }
        __syncthreads();
    }
    const int b = bbase + m;
    float* op = out + ((size_t)b * Lc + (l + 1)) * Qc;
#pragma unroll
    for (int qi = 0; qi < 6; ++qi) {
        const int qq = q0 + qi;
        if (qq < Qc) op[qq] = racc[qi] + blsh[qq];   // pure write (no out read)
    }
}

extern "C" void kernel_launch(void* const* d_in, const int* in_sizes, int n_in,
                              void* d_out, int out_size, void* d_ws, size_t ws_size,
                              hipStream_t stream) {
    const float* x    = (const float*)d_in[0];
    const float* bias = (const float*)d_in[1];
    const float* DW   = (const float*)d_in[2];
    const float* w0   = (const float*)d_in[3];
    const float* b0   = (const float*)d_in[4];
    const float* W1   = (const float*)d_in[5];
    const float* b1   = (const float*)d_in[6];
    const float* W2   = (const float*)d_in[7];
    const float* b2   = (const float*)d_in[8];
    const float* Wout = (const float*)d_in[9];
    const float* bout = (const float*)d_in[10];
    float* out = (float*)d_out;

    unsigned char* idxT = (unsigned char*)d_ws;
    unsigned int*  part = (unsigned int*)((char*)d_ws + 204800);

    k_idx<<<Lc, 256, 0, stream>>>(x, idxT);
    k_h1<<<LM1c * NCH, 1024, 0, stream>>>(W1, idxT, part);
    k_h2<<<400, 512, 0, stream>>>(part, W2, b1, b2, Wout, bout, bias, out);
    k_dca<<<Bc, 512, 0, stream>>>(DW, bias, w0, b0, idxT, out);  // last: += into 1..20
}

// Round 22
// 130.181 us; speedup vs baseline: 1.2382x; 1.2382x over previous
//
#include <hip/hip_runtime.h>

// arHOCA: L=200 positions, Q=21 alphabet, H=128 hidden, B=256 batch.
// x is one-hot => all "x @ W" contractions are gather-sums over idx[b,l].
//
// DCA mask (faithful to reference): mask loop is `for i in range(Q)`, so only
// row-blocks 1..20 / col-blocks 0..19 are active; mask[d,c]=1 iff blk(c)<blk(d).
// => DCA affects only output cols j < 441; for positions >= 21 out_dca = bias.
//
// Structure (R17/R20 optimum, 131.0 us, reproduced twice):
//  k_idx: one-hot -> uchar idxT.
//  k_h1:  chunked LDS-broadcast streamer (fp32 tile, bf16 partial sums);
//         2 lp per barrier (4 tile buffers). CH=48 (CH=32 and CH=64 both
//         measured worse: chunk overhead vs CU starvation).
//  k_h2:  partial-sum + b1 + lrelu A-stage, 128x128x128 fp32 GEMM + b2 + lrelu,
//         fused Wout epilogue; pure-writes out = NN + bout + bias.
//  k_dca: slim (runs LAST): pos 0 pure write, pos 1..20 += DCA gather.
//
// ws layout: idxT [200][256] uchar (51200 B, region reserved to 204800)
//            | part [199][5][256][128] bf16 (65208320 B).

#define Lc   200
#define Qc   21
#define Hc   128
#define Bc   256
#define LQc  4200
#define LM1c 199
#define CH   48    // lp chunk size
#define NCH  5     // max chunks per l

__device__ __forceinline__ unsigned int bf16rne(float f) {
    unsigned int u = __float_as_uint(f);
    return u + 0x7fffu + ((u >> 16) & 1u);   // take high 16 afterwards
}

// ---------------- K0: idxT[l][b] = argmax_c x[b,l,c] (uchar) ----------------
__global__ __launch_bounds__(256) void k_idx(const float* __restrict__ x,
                                             unsigned char* __restrict__ idxT) {
    const int l = blockIdx.x;       // 0..199
    const int b = threadIdx.x;      // 0..255
    const float* p = x + ((size_t)b * Lc + l) * Qc;
    int id = 0;
#pragma unroll
    for (int c = 0; c < Qc; ++c) id = (p[c] > 0.5f) ? c : id;
    idxT[l * Bc + b] = (unsigned char)id;   // coalesced byte store
}

// ---------------- K1 (slim, runs LAST): DCA gather for positions 0..20 ----------------
// pos 0:  out[b,0,q]  = bias[q] + w0[q] + b0[q] + sum_{lr=1..20} DW[lr*Q+idx, q]
// pos>=1: out[b,p,q] += sum_{lr=p+1..20} DW[lr*Q+idx[b,lr], p*Q+q]
__global__ __launch_bounds__(512) void k_dca(const float* __restrict__ DW,
                                             const float* __restrict__ bias,
                                             const float* __restrict__ w0,
                                             const float* __restrict__ b0,
                                             const unsigned char* __restrict__ idxT,
                                             float* __restrict__ out) {
    const int b = blockIdx.x;              // 0..255
    const int t = threadIdx.x;
    __shared__ int sidx[20];
    if (t < 20) sidx[t] = idxT[(t + 1) * Bc + b];
    __syncthreads();
    if (t >= 441) return;
    const int pos = t / 21, q = t - pos * 21;
    const int j = t;                       // j = pos*21 + q
    float acc = 0.f;
    for (int lr = pos + 1; lr <= 20; ++lr)
        acc += DW[(size_t)(lr * Qc + sidx[lr - 1]) * LQc + j];
    float* op = out + (size_t)b * LQc;
    if (pos == 0) op[j] = acc + bias[j] + w0[q] + b0[q];
    else          op[j] += acc;
}

// ---------------- K2: chunked LDS-broadcast partial sums (2 lp / barrier) ----------------
// part[l][c][b][h] = sum_{lp in chunk c, lp<=l} W1[l, lp*Q+idx[b,lp], h]
// Block = (l, chunk), 1024 threads. Thread = (hq 0..31, bg 0..31 of 8 batches).
// Four tile buffers as two ping-pong PAIRS: per loop body consume tiles k,k+1,
// stage k+2,k+3 into the other pair, ONE barrier. Writes target the pair whose
// readers finished before the previous barrier (same invariant as 2-buffer).
__global__ __launch_bounds__(1024, 2) void k_h1(const float* __restrict__ W1,
                                                const unsigned char* __restrict__ idxT,
                                                unsigned int* __restrict__ part) {
    const int bid = blockIdx.x;            // 0..994
    const int l = 198 - bid / NCH, c = bid % NCH;
    const int lo = c * CH;
    if (lo > l) return;                    // invalid chunk for this l
    const int hi = (l < lo + CH - 1) ? l : lo + CH - 1;
    const int n = hi - lo + 1;             // 1..48 iterations

    const int t = threadIdx.x;
    const int hq = t & 31;                 // h-quad: h = hq*4 .. hq*4+3
    const int bg = t >> 5;                 // batch group: b = bg*8 .. bg*8+7

    __shared__ __align__(16) float tile[4][Qc * 132];  // 2 ping-pong pairs
    __shared__ __align__(16) unsigned char idxs8[CH * Bc];

    // stage chunk idx bytes (n*256 B = n*16 int4), coalesced
    {
        const int4* isrc = (const int4*)(idxT + lo * Bc);
        int4* idst = (int4*)idxs8;
        if (t < n * 16) idst[t] = isrc[t];
    }

    // stage tiles 0 and 1 (672 float4 each): i -> row i>>5, col (i&31)*4
    const float* Wsrc = W1 + (size_t)l * (LQc * Hc) + (size_t)lo * (Qc * Hc);
    const int soff = (t >> 5) * 132 + (t & 31) * 4;
    if (t < 672) {
        *(float4*)&tile[0][soff] = ((const float4*)Wsrc)[t];
        if (n > 1)
            *(float4*)&tile[1][soff] = ((const float4*)(Wsrc + (size_t)(Qc * Hc)))[t];
    }
    __syncthreads();

    float4 acc[8];
#pragma unroll
    for (int j = 0; j < 8; ++j) acc[j] = (float4){0.f, 0.f, 0.f, 0.f};

#define ACCK(TB, KIDX) { \
        const unsigned int* ibw_ = (const unsigned int*)&idxs8[(KIDX) * Bc + bg * 8]; \
        const unsigned int u0_ = ibw_[0], u1_ = ibw_[1]; \
        const float* tb_ = &(TB)[hq * 4]; \
        { const float4 v = *(const float4*)(tb_ + (int)( u0_        & 0xffu) * 132); \
          acc[0].x += v.x; acc[0].y += v.y; acc[0].z += v.z; acc[0].w += v.w; } \
        { const float4 v = *(const float4*)(tb_ + (int)((u0_ >>  8) & 0xffu) * 132); \
          acc[1].x += v.x; acc[1].y += v.y; acc[1].z += v.z; acc[1].w += v.w; } \
        { const float4 v = *(const float4*)(tb_ + (int)((u0_ >> 16) & 0xffu) * 132); \
          acc[2].x += v.x; acc[2].y += v.y; acc[2].z += v.z; acc[2].w += v.w; } \
        { const float4 v = *(const float4*)(tb_ + (int)((u0_ >> 24) & 0xffu) * 132); \
          acc[3].x += v.x; acc[3].y += v.y; acc[3].z += v.z; acc[3].w += v.w; } \
        { const float4 v = *(const float4*)(tb_ + (int)( u1_        & 0xffu) * 132); \
          acc[4].x += v.x; acc[4].y += v.y; acc[4].z += v.z; acc[4].w += v.w; } \
        { const float4 v = *(const float4*)(tb_ + (int)((u1_ >>  8) & 0xffu) * 132); \
          acc[5].x += v.x; acc[5].y += v.y; acc[5].z += v.z; acc[5].w += v.w; } \
        { const float4 v = *(const float4*)(tb_ + (int)((u1_ >> 16) & 0xffu) * 132); \
          acc[6].x += v.x; acc[6].y += v.y; acc[6].z += v.z; acc[6].w += v.w; } \
        { const float4 v = *(const float4*)(tb_ + (int)((u1_ >> 24) & 0xffu) * 132); \
          acc[7].x += v.x; acc[7].y += v.y; acc[7].z += v.z; acc[7].w += v.w; } }

    int cur = 0;                            // current pair: buffers cur*2, cur*2+1
    for (int k = 0; k < n; k += 2) {
        // issue loads for tiles k+2, k+3 (1 float4/thread each)
        float4 p0, p1;
        const bool st0 = (k + 2 < n) && (t < 672);
        const bool st1 = (k + 3 < n) && (t < 672);
        if (st0) p0 = ((const float4*)(Wsrc + (size_t)(k + 2) * (Qc * Hc)))[t];
        if (st1) p1 = ((const float4*)(Wsrc + (size_t)(k + 3) * (Qc * Hc)))[t];
        // consume tiles k (and k+1) — HBM latency of p0/p1 hides under this
        ACCK(tile[cur * 2], k)
        if (k + 1 < n) ACCK(tile[cur * 2 + 1], k + 1)
        // write k+2/k+3 into the other pair, then ONE barrier
        if (st0) *(float4*)&tile[(cur ^ 1) * 2][soff] = p0;
        if (st1) *(float4*)&tile[(cur ^ 1) * 2 + 1][soff] = p1;
        __syncthreads();
        cur ^= 1;
    }
#undef ACCK

    // store partials as bf16: part[(l*5+c)][b][h]; 8B/lane x 32 lanes bursts
    unsigned int* pb = part + ((size_t)(l * NCH + c) * Bc + bg * 8) * (Hc / 2) + hq * 2;
#pragma unroll
    for (int j = 0; j < 8; ++j) {
        const unsigned int d0 = (bf16rne(acc[j].x) >> 16) | (bf16rne(acc[j].y) & 0xffff0000u);
        const unsigned int d1 = (bf16rne(acc[j].z) >> 16) | (bf16rne(acc[j].w) & 0xffff0000u);
        *(uint2*)(pb + (size_t)j * (Hc / 2)) = make_uint2(d0, d1);
    }
}

// ---------------- K3 (fused): h2 GEMM + Wout contraction -> out (pure write) ----------------
// Block = (l, batch-half), 512 threads (3.1 waves/SIMD). XCD-paired dispatch:
// both halves of l on one XCD. Writes out[b,l+1,q] = NN + bout + bias.
__global__ __launch_bounds__(512, 4) void k_h2(const unsigned int* __restrict__ part,
                                               const float* __restrict__ W2,
                                               const float* __restrict__ b1,
                                               const float* __restrict__ b2,
                                               const float* __restrict__ Wout,
                                               const float* __restrict__ bout,
                                               const float* __restrict__ bias,
                                               float* __restrict__ out) {
    const int d = blockIdx.x;              // 0..399
    const int g = d >> 4, r = d & 7, half = (d >> 3) & 1;
    const int l = g * 8 + r;
    if (l >= LM1c) return;                 // 2 idle blocks
    const int bbase = half * 128;
    const int t = threadIdx.x;
    const int tx = t & 15, ty = t >> 4;    // thread tile: 4(m) x 8(n); ty 0..31
    __shared__ float As[16][132];
    __shared__ float Bs[16][Hc];
    __shared__ float Ts[32][132];
    __shared__ float wl[Hc][24];           // Wout[l] padded; cols 21..23 = 0
    __shared__ float blsh[24];             // bout[l] + bias[(l+1)*21+..]; pad 0
    float acc[4][8];
#pragma unroll
    for (int i = 0; i < 4; ++i)
#pragma unroll
        for (int j = 0; j < 8; ++j) acc[i][j] = 0.f;
    // stage Wout[l] (128x21) + zero pad cols; stage fused output bias
    {
        const float* wsrc = Wout + (size_t)l * Hc * Qc;
        for (int i = t; i < Hc * Qc; i += 512) wl[i / Qc][i % Qc] = wsrc[i];
        if (t < Hc) { wl[t][21] = 0.f; wl[t][22] = 0.f; wl[t][23] = 0.f; }
        if (t < Qc) blsh[t] = bout[l * Qc + t] + bias[(l + 1) * Qc + t];
        else if (t < 24) blsh[t] = 0.f;
    }
    const int skk = t >> 5, sms = (t & 31) * 4;   // B-stage: 1 float4/thread
    const int am = t >> 2, akq = (t & 3) * 4;     // A-stage: m=am, k-quad akq
    const int nch = l / CH + 1;
    const unsigned int* pl = part + ((size_t)(l * NCH) * Bc + bbase + am) * (Hc / 2);
    const float* W2l = W2 + (size_t)l * Hc * Hc;
    for (int ks = 0; ks < 8; ++ks) {
        const int kcu = ks * 8 + (t & 3) * 2;     // uint col (2 bf16 per uint)
        float4 a0 = {0.f, 0.f, 0.f, 0.f};
        for (int cc = 0; cc < nch; ++cc) {
            const uint2 w = *(const uint2*)(pl + (size_t)cc * Bc * (Hc / 2) + kcu);
            a0.x += __uint_as_float(w.x << 16);
            a0.y += __uint_as_float(w.x & 0xffff0000u);
            a0.z += __uint_as_float(w.y << 16);
            a0.w += __uint_as_float(w.y & 0xffff0000u);
        }
        const float4 bb = *(const float4*)(b1 + l * Hc + ks * 16 + akq);
        a0.x += bb.x; a0.y += bb.y; a0.z += bb.z; a0.w += bb.w;
        a0.x = (a0.x >= 0.f) ? a0.x : 0.1f * a0.x;
        a0.y = (a0.y >= 0.f) ? a0.y : 0.1f * a0.y;
        a0.z = (a0.z >= 0.f) ? a0.z : 0.1f * a0.z;
        a0.w = (a0.w >= 0.f) ? a0.w : 0.1f * a0.w;
        const int kb = ks * 16 + skk;
        *(float4*)&Bs[skk][sms] = *(const float4*)(W2l + (size_t)kb * Hc + sms);
        As[akq + 0][am] = a0.x; As[akq + 1][am] = a0.y;
        As[akq + 2][am] = a0.z; As[akq + 3][am] = a0.w;
        __syncthreads();
#pragma unroll
        for (int k = 0; k < 16; ++k) {
            float avr[4], bvr[8];
            *(float4*)&avr[0] = *(const float4*)&As[k][ty * 4];
            *(float4*)&bvr[0] = *(const float4*)&Bs[k][tx * 8];
            *(float4*)&bvr[4] = *(const float4*)&Bs[k][tx * 8 + 4];
#pragma unroll
            for (int i = 0; i < 4; ++i)
#pragma unroll
                for (int j = 0; j < 8; ++j) acc[i][j] += avr[i] * bvr[j];
        }
        __syncthreads();
    }
    float bz[8];
    *(float4*)&bz[0] = *(const float4*)(b2 + l * Hc + tx * 8);
    *(float4*)&bz[4] = *(const float4*)(b2 + l * Hc + tx * 8 + 4);
    float res[4][8];
#pragma unroll
    for (int i = 0; i < 4; ++i)
#pragma unroll
        for (int j = 0; j < 8; ++j) {
            float v = acc[i][j] + bz[j];
            res[i][j] = (v >= 0.f) ? v : 0.1f * v;
        }
    // Epilogue: out[b, l+1, q] = sum_n res_T[n][m] * wl[n][q] + blsh[q].
    const int m = t & 127, qh = t >> 7;    // qh 0..3, wave-uniform
    const int q0 = qh * 6;                 // q 0..5 / 6..11 / 12..17 / 18..23(pad)
    float racc[6];
#pragma unroll
    for (int qi = 0; qi < 6; ++qi) racc[qi] = 0.f;
    for (int c = 0; c < 4; ++c) {
        if ((tx >> 2) == c) {
#pragma unroll
            for (int i = 0; i < 4; ++i)
#pragma unroll
                for (int j = 0; j < 8; ++j) Ts[(tx & 3) * 8 + j][ty * 4 + i] = res[i][j];
        }
        __syncthreads();
#pragma unroll 4
        for (int rr = 0; rr < 32; ++rr) {
            const float v = Ts[rr][m];     // 64 consecutive m per wave: free
            const float* wr = &wl[c * 32 + rr][q0];  // wave-uniform: broadcast
#pragma unroll
            for (int qi = 0; qi < 6; ++qi) racc[qi] += v * wr[qi];
        }
        __syncthreads();
    }
    const int b = bbase + m;
    float* op = out + ((size_t)b * Lc + (l + 1)) * Qc;
#pragma unroll
    for (int qi = 0; qi < 6; ++qi) {
        const int qq = q0 + qi;
        if (qq < Qc) op[qq] = racc[qi] + blsh[qq];   // pure write (no out read)
    }
}

extern "C" void kernel_launch(void* const* d_in, const int* in_sizes, int n_in,
                              void* d_out, int out_size, void* d_ws, size_t ws_size,
                              hipStream_t stream) {
    const float* x    = (const float*)d_in[0];
    const float* bias = (const float*)d_in[1];
    const float* DW   = (const float*)d_in[2];
    const float* w0   = (const float*)d_in[3];
    const float* b0   = (const float*)d_in[4];
    const float* W1   = (const float*)d_in[5];
    const float* b1   = (const float*)d_in[6];
    const float* W2   = (const float*)d_in[7];
    const float* b2   = (const float*)d_in[8];
    const float* Wout = (const float*)d_in[9];
    const float* bout = (const float*)d_in[10];
    float* out = (float*)d_out;

    unsigned char* idxT = (unsigned char*)d_ws;
    unsigned int*  part = (unsigned int*)((char*)d_ws + 204800);

    k_idx<<<Lc, 256, 0, stream>>>(x, idxT);
    k_h1<<<LM1c * NCH, 1024, 0, stream>>>(W1, idxT, part);
    k_h2<<<400, 512, 0, stream>>>(part, W2, b1, b2, Wout, bout, bias, out);
    k_dca<<<Bc, 512, 0, stream>>>(DW, bias, w0, b0, idxT, out);  // last: += into 1..20
}